// Round 7
// baseline (116.843 us; speedup 1.0000x reference)
//
#include <hip/hip_runtime.h>

#define N 8192
#define D 128
// (1/0.07) * log2(e): fold temperature AND base-2 conversion into A-side scale
#define SCALE_A 20.6098592f
#define NBLK 2080   // 64*65/2 upper-triangle 128x128 tiles

using short8  = __attribute__((ext_vector_type(8))) short;
using float4v = __attribute__((ext_vector_type(4))) float;

#if __has_builtin(__builtin_amdgcn_exp2f)
#define EXP2(x) __builtin_amdgcn_exp2f(x)
#else
#define EXP2(x) __expf((x) * 0.69314718f)
#endif

// float -> bf16 (RNE) as raw ushort
static __device__ inline unsigned int f2bf(float f) {
    union { float f; unsigned int u; } x;
    x.f = f;
    unsigned int u = x.u;
    return (u + 0x7FFFu + ((u >> 16) & 1u)) >> 16;
}

// Pre-pass: emb fp32 -> bf16 (unscaled, B-side) and bf16*SCALE_A (A-side).
// Also zeroes tot/pos and the ticket. 65536 threads x 16 elements.
__global__ __launch_bounds__(256) void cl_prep(
    const float* __restrict__ emb, unsigned short* __restrict__ bfB,
    unsigned short* __restrict__ bfA, float* __restrict__ tot,
    int* __restrict__ ticket)
{
    const int t = blockIdx.x * 256 + threadIdx.x;
    const float* p = emb + (size_t)t * 16;
    uint4 ob[2], oa[2];
    #pragma unroll
    for (int h = 0; h < 2; ++h) {
        float4v f0 = *(const float4v*)(p + h * 8);
        float4v f1 = *(const float4v*)(p + h * 8 + 4);
        ob[h].x = f2bf(f0[0]) | (f2bf(f0[1]) << 16);
        ob[h].y = f2bf(f0[2]) | (f2bf(f0[3]) << 16);
        ob[h].z = f2bf(f1[0]) | (f2bf(f1[1]) << 16);
        ob[h].w = f2bf(f1[2]) | (f2bf(f1[3]) << 16);
        oa[h].x = f2bf(f0[0] * SCALE_A) | (f2bf(f0[1] * SCALE_A) << 16);
        oa[h].y = f2bf(f0[2] * SCALE_A) | (f2bf(f0[3] * SCALE_A) << 16);
        oa[h].z = f2bf(f1[0] * SCALE_A) | (f2bf(f1[1] * SCALE_A) << 16);
        oa[h].w = f2bf(f1[2] * SCALE_A) | (f2bf(f1[3] * SCALE_A) << 16);
    }
    ((uint4*)bfB)[t * 2]     = ob[0];
    ((uint4*)bfB)[t * 2 + 1] = ob[1];
    ((uint4*)bfA)[t * 2]     = oa[0];
    ((uint4*)bfA)[t * 2 + 1] = oa[1];
    if (t < 2 * N) tot[t] = 0.f;    // tot and pos are contiguous
    if (t == 0) *ticket = 0;
}

// Symmetric-exploiting main kernel: exp(sim) and the pos mask are symmetric,
// so tile (bi,bj) with bi<bj contributes its ROW sums to rows of block bi and
// its COLUMN sums to rows of block bj. Only the 2080 upper-triangle tiles are
// computed (~2x less MFMA/epilogue/B-traffic than the full 4096).
// One 128x128 tile per block, ONE barrier per block: with 2 resident blocks/CU
// one block's staging overlaps the other's MFMA+epilogue (block-level
// pipelining — intra-block K-loops were barrier/latency-bound, R5/R6).
// Register floor ~184 unified (R6 measured 120+64) -> (256,2); >=3 spills.
// NO agent-scope fences (R4: per-block L2 invalidate thrash). Producer order =
// s_waitcnt vmcnt(0) + barrier before a RELAXED ticket add.
__global__ __launch_bounds__(256, 2) void cl_main(
    const unsigned short* __restrict__ bfA, const unsigned short* __restrict__ bfB,
    const int* __restrict__ labels,
    float* __restrict__ tot, float* __restrict__ pos,
    int* __restrict__ ticket, float* __restrict__ out)
{
    __shared__ uint4 ldsB[128 * 16];  // 128x128 bf16 B-tile, 16B chunks, XOR-swizzled
    __shared__ float sred[2][4];
    __shared__ int s_ticket;

    const int tid  = threadIdx.x;
    const int lane = tid & 63;
    const int wave = tid >> 6;
    const int q    = lane >> 4;   // quad id 0..3
    const int c    = lane & 15;

    // ---- decode upper-triangle tile index: t -> (bi, bj), bi <= bj ----
    const int t = blockIdx.x;
    int bi = (int)((129.0f - sqrtf(16641.0f - 8.0f * (float)t)) * 0.5f);
    bi = bi < 0 ? 0 : (bi > 63 ? 63 : bi);
    while (bi > 0 && 64 * bi - bi * (bi - 1) / 2 > t) --bi;
    while (64 * (bi + 1) - (bi + 1) * bi / 2 <= t) ++bi;
    const int bj   = bi + (t - (64 * bi - bi * (bi - 1) / 2));
    const bool diag = (bi == bj);
    const int rbase = bi * 128;            // A-side rows
    const int cbase = bj * 128;            // B-side rows (= columns)
    const int rw    = rbase + wave * 32;

    // ---- A fragments: 16B loads from prescaled bf16, A-layout m=lane&15,k=q*8+j
    short8 afrag[2][4];
    int rowlab[2][4];
    #pragma unroll
    for (int tr = 0; tr < 2; ++tr) {
        const int arow = rw + tr * 16 + c;
        #pragma unroll
        for (int ks = 0; ks < 4; ++ks)
            afrag[tr][ks] = *(const short8*)(bfA + (size_t)arow * D + ks * 32 + q * 8);
        #pragma unroll
        for (int reg = 0; reg < 4; ++reg)
            rowlab[tr][reg] = labels[rw + tr * 16 + q * 4 + reg];
    }

    // ---- stage B tile (block bj's 128 rows): coalesced uint4 -> swizzled LDS
    {
        const uint4* bfB4 = (const uint4*)bfB;
        #pragma unroll
        for (int i = 0; i < 8; ++i) {
            const int g     = tid + i * 256;
            const int brow  = g >> 4;
            const int chunk = g & 15;
            uint4 u = bfB4[(size_t)(cbase + brow) * 16 + chunk];
            ldsB[brow * 16 + (chunk ^ (brow & 15))] = u;
        }
    }
    int collab[8];
    #pragma unroll
    for (int tc = 0; tc < 8; ++tc) collab[tc] = labels[cbase + tc * 16 + c];
    __syncthreads();   // the only barrier before the finalize handshake

    // ---- MFMA: 2 tile-rows x 8 tile-cols, K=128 in 4 steps ----
    float4v acc[2][8];
    #pragma unroll
    for (int tr = 0; tr < 2; ++tr)
        #pragma unroll
        for (int tc = 0; tc < 8; ++tc) {
            float4v z = {0.f, 0.f, 0.f, 0.f};
            acc[tr][tc] = z;
        }
    const short8* ldsS = (const short8*)ldsB;
    #pragma unroll
    for (int ks = 0; ks < 4; ++ks) {
        const short8* pk = ldsS + c * 16 + ((ks * 4 + q) ^ c);
        #pragma unroll
        for (int tc = 0; tc < 8; ++tc) {
            short8 b = pk[tc * 256];
            #pragma unroll
            for (int tr = 0; tr < 2; ++tr)
                acc[tr][tc] = __builtin_amdgcn_mfma_f32_16x16x32_bf16(
                    afrag[tr][ks], b, acc[tr][tc], 0, 0, 0);
        }
    }

    // ---- epilogue: exp2, masks, row-accumulate + (off-diag) col-accumulate ----
    float tot_a[2][4] = {{0.f,0.f,0.f,0.f},{0.f,0.f,0.f,0.f}};
    float pos_a[2][4] = {{0.f,0.f,0.f,0.f},{0.f,0.f,0.f,0.f}};
    #pragma unroll
    for (int tc = 0; tc < 8; ++tc) {
        const int lc = collab[tc];
        const int ctile = cbase + tc * 16;
        float colt = 0.f, colp = 0.f;
        #pragma unroll
        for (int tr = 0; tr < 2; ++tr) {
            const bool diag_tile = diag && (rw + tr * 16 == ctile);  // wave-uniform
            #pragma unroll
            for (int reg = 0; reg < 4; ++reg) {
                float v = EXP2(acc[tr][tc][reg]);
                if (diag_tile && (q * 4 + reg) == c) v = 0.f;  // r == c
                const bool m = (rowlab[tr][reg] == lc);
                tot_a[tr][reg] += v;
                if (m) pos_a[tr][reg] += v;
                colt += v;
                if (m) colp += v;
            }
        }
        if (!diag) {
            // col sums: reduce over the 4 row-quads (lane bits 4,5)
            colt += __shfl_xor(colt, 16, 64);
            colt += __shfl_xor(colt, 32, 64);
            colp += __shfl_xor(colp, 16, 64);
            colp += __shfl_xor(colp, 32, 64);
            if (q == 0) {   // lanes 0..15 hold cols ctile+c
                atomicAdd(&tot[ctile + c], colt);
                atomicAdd(&pos[ctile + c], colp);
            }
        }
    }

    // ---- row sums: reduce over the 16 column-lanes, one atomic per row ----
    #pragma unroll
    for (int tr = 0; tr < 2; ++tr)
        #pragma unroll
        for (int reg = 0; reg < 4; ++reg) {
            float tt = tot_a[tr][reg];
            float pp = pos_a[tr][reg];
            #pragma unroll
            for (int m = 1; m < 16; m <<= 1) {
                tt += __shfl_xor(tt, m, 64);
                pp += __shfl_xor(pp, m, 64);
            }
            if (c == 0) {
                const int r = rw + tr * 16 + q * 4 + reg;
                atomicAdd(&tot[r], tt);
                atomicAdd(&pos[r], pp);
            }
        }

    // ---- last-block finalize: completion-wait + relaxed ticket (NO cache ops)
    asm volatile("s_waitcnt vmcnt(0)" ::: "memory");  // our atomics committed
    __syncthreads();
    if (tid == 0)
        s_ticket = __hip_atomic_fetch_add(ticket, 1, __ATOMIC_RELAXED,
                                          __HIP_MEMORY_SCOPE_AGENT);
    __syncthreads();
    if (s_ticket != NBLK - 1) return;

    float lsum = 0.f, lcnt = 0.f;
    #pragma unroll 4
    for (int i = tid; i < N; i += 256) {
        const float tt = __hip_atomic_load(&tot[i], __ATOMIC_RELAXED,
                                           __HIP_MEMORY_SCOPE_AGENT);
        const float pp = __hip_atomic_load(&pos[i], __ATOMIC_RELAXED,
                                           __HIP_MEMORY_SCOPE_AGENT);
        const float loss = -__logf(pp / (tt + 1e-8f) + 1e-8f);
        if (pp > 0.f) { lsum += loss; lcnt += 1.f; }   // valid <=> pos>0
    }
    #pragma unroll
    for (int m = 1; m < 64; m <<= 1) {
        lsum += __shfl_xor(lsum, m, 64);
        lcnt += __shfl_xor(lcnt, m, 64);
    }
    if (lane == 0) { sred[0][wave] = lsum; sred[1][wave] = lcnt; }
    __syncthreads();
    if (tid == 0) {
        const float s = sred[0][0] + sred[0][1] + sred[0][2] + sred[0][3];
        const float n = sred[1][0] + sred[1][1] + sred[1][2] + sred[1][3];
        out[0] = (n > 0.f) ? s / fmaxf(n, 1.f) : 0.f;
    }
}

extern "C" void kernel_launch(void* const* d_in, const int* in_sizes, int n_in,
                              void* d_out, int out_size, void* d_ws, size_t ws_size,
                              hipStream_t stream) {
    const float* emb  = (const float*)d_in[0];
    const int* labels = (const int*)d_in[1];
    unsigned short* bfB = (unsigned short*)d_ws;                       // 2 MB
    unsigned short* bfA = bfB + (size_t)N * D;                         // 2 MB
    float* tot    = (float*)(bfA + (size_t)N * D);
    float* pos    = tot + N;
    int*   ticket = (int*)(pos + N);

    cl_prep<<<256, 256, 0, stream>>>(emb, bfB, bfA, tot, ticket);
    cl_main<<<NBLK, 256, 0, stream>>>(bfA, bfB, labels, tot, pos,
                                      ticket, (float*)d_out);
}